// Round 1
// baseline (26.568 us; speedup 1.0000x reference)
//
#include <hip/hip_runtime.h>

#define NN 262144
#define DD 32
#define HH 31
#define KK 21

// LDS footprint: W1 (21*31*31=20181 f) + b1 (651) + W2 (651) + b2 (21)
//              + a (31) + b (31)  = 21566 floats = 86264 B  -> 1 block/CU.
__global__ __launch_bounds__(1024) void mlp_bucket_kernel(
    const float* __restrict__ x,
    const float* __restrict__ a,
    const float* __restrict__ b,
    const float* __restrict__ W1,
    const float* __restrict__ b1,
    const float* __restrict__ W2,
    const float* __restrict__ b2,
    float* __restrict__ out)
{
    __shared__ float sW1[KK * HH * HH];
    __shared__ float sb1[KK * HH];
    __shared__ float sW2[KK * HH];
    __shared__ float sb2[KK];
    __shared__ float sa[HH];
    __shared__ float sb[HH];

    const int tid = threadIdx.x;

    for (int i = tid; i < KK * HH * HH; i += 1024) sW1[i] = W1[i];
    for (int i = tid; i < KK * HH; i += 1024) { sb1[i] = b1[i]; sW2[i] = W2[i]; }
    if (tid < KK) sb2[tid] = b2[tid];
    if (tid < HH) { sa[tid] = a[tid]; sb[tid] = b[tid]; }
    __syncthreads();

    const int n = blockIdx.x * 1024 + tid;

    // Load the full 128-byte row as 8x float4.
    float row[DD];
    const float4* xp = reinterpret_cast<const float4*>(x) + n * (DD / 4);
    #pragma unroll
    for (int i = 0; i < DD / 4; ++i) {
        float4 v = xp[i];
        row[4 * i + 0] = v.x;
        row[4 * i + 1] = v.y;
        row[4 * i + 2] = v.z;
        row[4 * i + 3] = v.w;
    }

    const float t = row[0];

    float feats[HH];
    #pragma unroll
    for (int j = 0; j < HH; ++j) feats[j] = fmaf(row[j + 1], sa[j], sb[j]);

    // Bucket: exact same comparisons as reference. edges[k] = k/10 (f32),
    // last edge 1000.
    const float edges[KK + 1] = {
        0.0f, 0.1f, 0.2f, 0.3f, 0.4f, 0.5f, 0.6f, 0.7f, 0.8f, 0.9f, 1.0f,
        1.1f, 1.2f, 1.3f, 1.4f, 1.5f, 1.6f, 1.7f, 1.8f, 1.9f, 2.0f, 1000.0f
    };
    int k = -1;
    #pragma unroll
    for (int j = 0; j < KK; ++j) {
        if (t > edges[j] && t <= edges[j + 1]) k = j;
    }

    float res = 0.0f;
    if (k >= 0) {
        const float* __restrict__ w1k = sW1 + k * (HH * HH);
        const float* __restrict__ b1k = sb1 + k * HH;
        const float* __restrict__ w2k = sW2 + k * HH;
        float acc = sb2[k];
        for (int e = 0; e < HH; ++e) {
            float h = b1k[e];
            #pragma unroll
            for (int d = 0; d < HH; ++d) h = fmaf(feats[d], w1k[d * HH + e], h);
            h = (h >= 0.0f) ? h : 0.1f * h;
            acc = fmaf(h, w2k[e], acc);
        }
        res = acc;
    }

    out[n] = res;
}

extern "C" void kernel_launch(void* const* d_in, const int* in_sizes, int n_in,
                              void* d_out, int out_size, void* d_ws, size_t ws_size,
                              hipStream_t stream) {
    const float* x  = (const float*)d_in[0];
    const float* a  = (const float*)d_in[1];
    const float* b  = (const float*)d_in[2];
    const float* W1 = (const float*)d_in[3];
    const float* b1 = (const float*)d_in[4];
    const float* W2 = (const float*)d_in[5];
    const float* b2 = (const float*)d_in[6];
    float* out = (float*)d_out;

    dim3 grid(NN / 1024);
    dim3 block(1024);
    hipLaunchKernelGGL(mlp_bucket_kernel, grid, block, 0, stream,
                       x, a, b, W1, b1, W2, b2, out);
}